// Round 4
// baseline (12253.630 us; speedup 1.0000x reference)
//
#include <hip/hip_runtime.h>
#include <math.h>

#define K_NN 20
#define NEG_SLOPE 0.2f

constexpr int CHUNK = 512;   // j-chunk per partial top-20 list (N/CHUNK = 32 lists)
constexpr int L1SEG = 8;     // emergency-fallback segmentation
constexpr int TJ    = 128;

// ---------------------------------------------------------------------------
__device__ __forceinline__ void insert_sorted(float (&dl)[K_NN], int (&il)[K_NN],
                                              float d, int idx) {
    if (d < dl[K_NN - 1]) {
        dl[K_NN - 1] = d; il[K_NN - 1] = idx;
#pragma unroll
        for (int p = K_NN - 1; p > 0; --p) {
            if (dl[p] < dl[p - 1]) {   // strict <: earlier (lower-index) ties stay first
                float td = dl[p]; dl[p] = dl[p - 1]; dl[p - 1] = td;
                int   ti = il[p]; il[p] = il[p - 1]; il[p - 1] = ti;
            }
        }
    }
}

// drain the per-thread LDS candidate buffer into the sorted register list
__device__ __forceinline__ void drain_buf(const float* bufD, const int* bufI, int tid,
                                          int& cnt, float (&dl)[K_NN], int (&il)[K_NN]) {
    for (int t = 0; t < cnt; ++t)
        insert_sorted(dl, il, bufD[tid + 256 * t], bufI[tid + 256 * t]);
    cnt = 0;
}

// ---------------------------------------------------------------------------
// sq[i] = sum_c x[i][c]^2   (ascending-c FMA chain; must match dot order)
template<int C>
__global__ __launch_bounds__(256) void sqnorm_kernel(const float* __restrict__ x,
                                                     float* __restrict__ sq, int N) {
    int i = blockIdx.x * 256 + threadIdx.x;
    if (i < N) {
        float s = 0.f;
#pragma unroll
        for (int c = 0; c < C; ++c) { float v = x[i * C + c]; s += v * v; }
        sq[i] = s;
    }
}

// x4[i] = {x,y,z, sq}  (same fp chain as sqnorm<3>)
__global__ __launch_bounds__(256) void pack3_kernel(const float* __restrict__ x,
                                                    float4* __restrict__ x4, int N) {
    int i = blockIdx.x * 256 + threadIdx.x;
    if (i < N) {
        float a = x[i * 3], b = x[i * 3 + 1], c = x[i * 3 + 2];
        float s = a * a; s += b * b; s += c * c;
        x4[i] = make_float4(a, b, c, s);
    }
}

// ---------------------------------------------------------------------------
// Layer-1 kNN scan: thread = query, grid.y = j-chunk. Broadcast x4 loads,
// buffered-insert selection (rare drains replace per-item bubble).
__global__ __launch_bounds__(256) void knn_scan3_kernel(const float4* __restrict__ x4,
                                                        float* __restrict__ pdist,
                                                        int* __restrict__ pidx, int N) {
    __shared__ float bufD[16 * 256];
    __shared__ int   bufI[16 * 256];
    const int tid = threadIdx.x;
    const int q   = blockIdx.x * 256 + tid;
    const int j0  = blockIdx.y * CHUNK;

    float4 qv = x4[q];
    const float qsq = qv.w;

    float dl[K_NN]; int il[K_NN];
#pragma unroll
    for (int p = 0; p < K_NN; ++p) { dl[p] = __builtin_inff(); il[p] = 0; }
    int cnt = 0;

    for (int jj = 0; jj < CHUNK; jj += 8) {
#pragma unroll
        for (int t = 0; t < 8; ++t) {
            float4 pv = x4[j0 + jj + t];                 // broadcast (L1-hit)
            float dot = qv.x * pv.x; dot += qv.y * pv.y; dot += qv.z * pv.z;
            float d = (qsq - 2.f * dot) + pv.w;
            if (d < dl[K_NN - 1]) {
                bufD[tid + 256 * cnt] = d;
                bufI[tid + 256 * cnt] = j0 + jj + t;
                ++cnt;
            }
        }
        if (__any(cnt >= 8)) drain_buf(bufD, bufI, tid, cnt, dl, il);
    }
    drain_buf(bufD, bufI, tid, cnt, dl, il);

    const size_t base = ((size_t)q * 32 + blockIdx.y) * K_NN;
#pragma unroll
    for (int p = 0; p < K_NN; ++p) { pdist[base + p] = dl[p]; pidx[base + p] = il[p]; }
}

// ---------------------------------------------------------------------------
// xT[c][i] = x[i][c]  (C = 64)
__global__ __launch_bounds__(256) void transpose64_kernel(const float* __restrict__ xin,
                                                          float* __restrict__ xT, int N) {
    int i = blockIdx.x * 256 + threadIdx.x;
    int c = blockIdx.y;
    xT[(size_t)c * N + i] = xin[(size_t)i * 64 + c];
}

// ---------------------------------------------------------------------------
// Distance GEMM tile, TRANSPOSED store: DT[j_local][q] = d(q, j0+j_local).
// 128x128 tile, 8x8/thread, coalesced float4 staging from xT, swizzled pT.
__global__ __launch_bounds__(256) void distT_kernel(const float* __restrict__ xT,
                                                    const float* __restrict__ sq,
                                                    float* __restrict__ DT,
                                                    int N, int j0, int pbBits) {
    __shared__ float qT[64][128];
    __shared__ float pT[64][140];
    __shared__ float qsq_s[128];
    __shared__ float psq_s[140];

    const int tid = threadIdx.x;
    const int qb  = blockIdx.x >> pbBits;
    const int pb  = blockIdx.x & ((1 << pbBits) - 1);
    const int q0  = qb * 128;
    const int p0  = pb * 128;   // local row base within segment

#pragma unroll
    for (int k = 0; k < 8; ++k) {
        int idx = tid + 256 * k;
        int c   = idx >> 5;
        int ch  = idx & 31;
        float4 qv = *(const float4*)&xT[(size_t)c * N + q0 + ch * 4];
        *(float4*)&qT[c][ch * 4] = qv;
        float4 pv = *(const float4*)&xT[(size_t)c * N + j0 + p0 + ch * 4];
        *(float4*)&pT[c][ch * 4 + 4 * (ch >> 3)] = pv;   // swizzle s(4*ch)
    }
    if (tid < 128) {
        qsq_s[tid] = sq[q0 + tid];
    } else {
        int t = tid - 128;
        psq_s[t + 4 * (t >> 5)] = sq[j0 + p0 + t];
    }
    __syncthreads();

    const int qg   = tid >> 4;
    const int pg   = tid & 15;
    const int qcol = qg * 8;
    const int pcol = pg * 8 + 4 * (pg >> 2);

    float acc[8][8];
#pragma unroll
    for (int i = 0; i < 8; ++i)
#pragma unroll
        for (int j = 0; j < 8; ++j) acc[i][j] = 0.f;

#pragma unroll 4
    for (int c = 0; c < 64; ++c) {
        float4 qa  = *(const float4*)&qT[c][qcol];
        float4 qb4 = *(const float4*)&qT[c][qcol + 4];
        float4 pa  = *(const float4*)&pT[c][pcol];
        float4 pb4 = *(const float4*)&pT[c][pcol + 4];
        float qf[8] = {qa.x, qa.y, qa.z, qa.w, qb4.x, qb4.y, qb4.z, qb4.w};
        float pf[8] = {pa.x, pa.y, pa.z, pa.w, pb4.x, pb4.y, pb4.z, pb4.w};
#pragma unroll
        for (int i = 0; i < 8; ++i)
#pragma unroll
            for (int j = 0; j < 8; ++j) acc[i][j] += qf[i] * pf[j];
    }

    float qsv[8];
#pragma unroll
    for (int i = 0; i < 8; ++i) qsv[i] = qsq_s[qcol + i];

#pragma unroll
    for (int jj = 0; jj < 8; ++jj) {
        float ps = psq_s[pcol + jj];                 // swizzled read, same value
        float4 o0, o1;
        o0.x = (qsv[0] - 2.f * acc[0][jj]) + ps;
        o0.y = (qsv[1] - 2.f * acc[1][jj]) + ps;
        o0.z = (qsv[2] - 2.f * acc[2][jj]) + ps;
        o0.w = (qsv[3] - 2.f * acc[3][jj]) + ps;
        o1.x = (qsv[4] - 2.f * acc[4][jj]) + ps;
        o1.y = (qsv[5] - 2.f * acc[5][jj]) + ps;
        o1.z = (qsv[6] - 2.f * acc[6][jj]) + ps;
        o1.w = (qsv[7] - 2.f * acc[7][jj]) + ps;
        float* dst = DT + (size_t)(p0 + pg * 8 + jj) * N + q0 + qcol;
        *(float4*)dst       = o0;
        *(float4*)(dst + 4) = o1;
    }
}

// ---------------------------------------------------------------------------
// Select from transposed distances: thread = query, grid.y = j-chunk of the
// current segment. Lane-coalesced column reads + buffered insert.
__global__ __launch_bounds__(256) void select_kernel(const float* __restrict__ DT,
                                                     float* __restrict__ pdist,
                                                     int* __restrict__ pidx,
                                                     int N, int jglobBase) {
    __shared__ float bufD[16 * 256];
    __shared__ int   bufI[16 * 256];
    const int tid = threadIdx.x;
    const int q   = blockIdx.x * 256 + tid;
    const int jl0 = blockIdx.y * CHUNK;
    const int jg0 = jglobBase + jl0;

    float dl[K_NN]; int il[K_NN];
#pragma unroll
    for (int p = 0; p < K_NN; ++p) { dl[p] = __builtin_inff(); il[p] = 0; }
    int cnt = 0;

    const float* col = DT + (size_t)jl0 * N + q;
    for (int jj = 0; jj < CHUNK; jj += 8) {
#pragma unroll
        for (int t = 0; t < 8; ++t) {
            float d = col[(size_t)(jj + t) * N];
            if (d < dl[K_NN - 1]) {
                bufD[tid + 256 * cnt] = d;
                bufI[tid + 256 * cnt] = jg0 + jj + t;
                ++cnt;
            }
        }
        if (__any(cnt >= 8)) drain_buf(bufD, bufI, tid, cnt, dl, il);
    }
    drain_buf(bufD, bufI, tid, cnt, dl, il);

    const size_t base = ((size_t)q * 32 + (jg0 >> 9)) * K_NN;
#pragma unroll
    for (int p = 0; p < K_NN; ++p) { pdist[base + p] = dl[p]; pidx[base + p] = il[p]; }
}

// ---------------------------------------------------------------------------
// Emergency fused kNN (round-1 proven), used only if workspace is tiny.
template<int C>
__global__ __launch_bounds__(256) void knn_partial_kernel(const float* __restrict__ x,
                                                          const float* __restrict__ sq,
                                                          float* __restrict__ pdist,
                                                          int* __restrict__ pidx, int N) {
    __shared__ float tile[TJ * C];
    __shared__ float tsq[TJ];

    const int qblk = blockIdx.x / L1SEG;
    const int seg  = blockIdx.x % L1SEG;
    const int q    = qblk * 256 + threadIdx.x;
    const int segLen = N / L1SEG;
    const int j0   = seg * segLen;

    float qf[C];
#pragma unroll
    for (int c = 0; c < C; ++c) qf[c] = x[q * C + c];
    const float qsq = sq[q];

    float dl[K_NN]; int il[K_NN];
#pragma unroll
    for (int p = 0; p < K_NN; ++p) { dl[p] = __builtin_inff(); il[p] = 0; }

    for (int t0 = 0; t0 < segLen; t0 += TJ) {
        __syncthreads();
        for (int u = threadIdx.x; u < TJ * C; u += 256)
            tile[u] = x[(j0 + t0) * C + u];
        for (int u = threadIdx.x; u < TJ; u += 256)
            tsq[u] = sq[j0 + t0 + u];
        __syncthreads();

        for (int t = 0; t < TJ; ++t) {
            float dot = 0.f;
#pragma unroll
            for (int c = 0; c < C; ++c) dot += qf[c] * tile[t * C + c];
            float d = qsq - 2.f * dot + tsq[t];
            insert_sorted(dl, il, d, j0 + t0 + t);
        }
    }

    const long base = ((long)q * L1SEG + seg) * K_NN;
#pragma unroll
    for (int p = 0; p < K_NN; ++p) { pdist[base + p] = dl[p]; pidx[base + p] = il[p]; }
}

// ---------------------------------------------------------------------------
// Merge nseg sorted partial lists -> final top-20 per query.
__global__ __launch_bounds__(256) void knn_merge_kernel(const float* __restrict__ pdist,
                                                        const int* __restrict__ pidx,
                                                        int* __restrict__ knn,
                                                        int N, int nseg) {
    int q = blockIdx.x * 256 + threadIdx.x;
    if (q >= N) return;
    float dl[K_NN]; int il[K_NN];
#pragma unroll
    for (int p = 0; p < K_NN; ++p) { dl[p] = __builtin_inff(); il[p] = 0; }

    for (int s = 0; s < nseg; ++s) {
        const long base = ((long)q * nseg + s) * K_NN;
        for (int p = 0; p < K_NN; ++p) {
            float d = pdist[base + p];
            if (!(d < dl[K_NN - 1])) break;   // sorted ascending
            insert_sorted(dl, il, d, pidx[base + p]);
        }
    }
#pragma unroll
    for (int p = 0; p < K_NN; ++p) knn[(long)q * K_NN + p] = il[p];
}

// ---------------------------------------------------------------------------
template<int C, int F>
__global__ __launch_bounds__(256) void proj_kernel(const float* __restrict__ x,
                                                   const float* __restrict__ W,
                                                   const float* __restrict__ b,
                                                   float* __restrict__ A,
                                                   float* __restrict__ U, int N) {
    int gid = blockIdx.x * 256 + threadIdx.x;
    int i = gid / F, f = gid % F;
    if (i >= N) return;
    float a = b[f], u = 0.f;
#pragma unroll
    for (int c = 0; c < C; ++c) {
        float xv = x[i * C + c];
        a += xv * W[c * F + f];
        u += xv * W[(C + c) * F + f];
    }
    A[(long)i * F + f] = a;
    U[(long)i * F + f] = u;
}

template<int F>
__global__ __launch_bounds__(256) void agg_kernel(const float* __restrict__ A,
                                                  const float* __restrict__ U,
                                                  const int* __restrict__ knn,
                                                  float* __restrict__ out, int N) {
    int gid = blockIdx.x * 256 + threadIdx.x;
    int i = gid / F, f = gid % F;
    if (i >= N) return;
    float a = A[(long)i * F + f] - U[(long)i * F + f];
    float m = -__builtin_inff();
#pragma unroll
    for (int k = 0; k < K_NN; ++k) {
        int j = knn[(long)i * K_NN + k];
        float v = a + U[(long)j * F + f];
        v = fmaxf(v, v * NEG_SLOPE);
        m = fmaxf(m, v);
    }
    out[(long)i * F + f] = m;
}

// ---------------------------------------------------------------------------
extern "C" void kernel_launch(void* const* d_in, const int* in_sizes, int n_in,
                              void* d_out, int out_size, void* d_ws, size_t ws_size,
                              hipStream_t stream) {
    const float* x  = (const float*)d_in[0];
    const float* W1 = (const float*)d_in[1];
    const float* b1 = (const float*)d_in[2];
    const float* W2 = (const float*)d_in[3];
    const float* b2 = (const float*)d_in[4];
    const float* W3 = (const float*)d_in[5];
    const float* b3 = (const float*)d_in[6];
    const int N = in_sizes[0] / 3;  // 16384

    float* ws  = (float*)d_ws;
    float* sq  = ws;                               // N
    float* A   = sq + N;                           // 128N
    float* U   = A + (size_t)N * 128;              // 128N
    float* h1  = U + (size_t)N * 128;              // 64N
    float* h2  = h1 + (size_t)N * 64;              // 64N
    float4* x4 = (float4*)(h2 + (size_t)N * 64);   // 4N
    float* xT  = (float*)(x4 + N);                 // 64N
    float* pd  = xT + (size_t)N * 64;              // 640N
    int* pidx  = (int*)(pd + (size_t)N * 640);     // 640N
    int* knn   = pidx + (size_t)N * 640;           // 20N
    float* DT  = (float*)(knn + (size_t)N * 20);   // N * segLenD
    float* out = (float*)d_out;

    const size_t wsW  = ws_size / 4;
    const size_t nonD = (size_t)N * 1753;
    int nsegD = 0;
    {
        const int cands[5] = {1, 2, 4, 8, 16};
        for (int ci = 0; ci < 5; ++ci) {
            size_t need = nonD + (size_t)N * (size_t)(N / cands[ci]);
            if (need <= wsW) { nsegD = cands[ci]; break; }
        }
    }

    const int qBlocks = N / 256;
    const int nChunk  = N / CHUNK;   // 32

    if (nsegD) {
        // ---- Layer 1 (C=3 -> F=64): scan path ----
        pack3_kernel<<<qBlocks, 256, 0, stream>>>(x, x4, N);
        knn_scan3_kernel<<<dim3(qBlocks, nChunk), 256, 0, stream>>>(x4, pd, pidx, N);
        knn_merge_kernel<<<qBlocks, 256, 0, stream>>>(pd, pidx, knn, N, nChunk);
        proj_kernel<3, 64><<<(N * 64) / 256, 256, 0, stream>>>(x, W1, b1, A, U, N);
        agg_kernel<64><<<(N * 64) / 256, 256, 0, stream>>>(A, U, knn, h1, N);

        const int segLenD = N / nsegD;
        const int pbCount = segLenD / 128;
        const int pbBits  = 31 - __builtin_clz(pbCount);

        // ---- Layer 2 (C=64 -> F=64) ----
        sqnorm_kernel<64><<<qBlocks, 256, 0, stream>>>(h1, sq, N);
        transpose64_kernel<<<dim3(qBlocks, 64), 256, 0, stream>>>(h1, xT, N);
        for (int s = 0; s < nsegD; ++s) {
            distT_kernel<<<(N / 128) * pbCount, 256, 0, stream>>>(xT, sq, DT, N,
                                                                  s * segLenD, pbBits);
            select_kernel<<<dim3(qBlocks, segLenD / CHUNK), 256, 0, stream>>>(
                DT, pd, pidx, N, s * segLenD);
        }
        knn_merge_kernel<<<qBlocks, 256, 0, stream>>>(pd, pidx, knn, N, nChunk);
        proj_kernel<64, 64><<<(N * 64) / 256, 256, 0, stream>>>(h1, W2, b2, A, U, N);
        agg_kernel<64><<<(N * 64) / 256, 256, 0, stream>>>(A, U, knn, h2, N);

        // ---- Layer 3 (C=64 -> F=128) ----
        sqnorm_kernel<64><<<qBlocks, 256, 0, stream>>>(h2, sq, N);
        transpose64_kernel<<<dim3(qBlocks, 64), 256, 0, stream>>>(h2, xT, N);
        for (int s = 0; s < nsegD; ++s) {
            distT_kernel<<<(N / 128) * pbCount, 256, 0, stream>>>(xT, sq, DT, N,
                                                                  s * segLenD, pbBits);
            select_kernel<<<dim3(qBlocks, segLenD / CHUNK), 256, 0, stream>>>(
                DT, pd, pidx, N, s * segLenD);
        }
        knn_merge_kernel<<<qBlocks, 256, 0, stream>>>(pd, pidx, knn, N, nChunk);
        proj_kernel<64, 128><<<(N * 128) / 256, 256, 0, stream>>>(h2, W3, b3, A, U, N);
        agg_kernel<128><<<(N * 128) / 256, 256, 0, stream>>>(A, U, knn, out, N);
    } else {
        // ---- emergency fallback (tiny ws): round-1 structure ----
        float* pd8 = h2 + (size_t)N * 64;
        int* pidx8 = (int*)(pd8 + (size_t)N * L1SEG * K_NN);
        int* knn8  = pidx8 + (size_t)N * L1SEG * K_NN;

        sqnorm_kernel<3><<<qBlocks, 256, 0, stream>>>(x, sq, N);
        knn_partial_kernel<3><<<qBlocks * L1SEG, 256, 0, stream>>>(x, sq, pd8, pidx8, N);
        knn_merge_kernel<<<qBlocks, 256, 0, stream>>>(pd8, pidx8, knn8, N, L1SEG);
        proj_kernel<3, 64><<<(N * 64) / 256, 256, 0, stream>>>(x, W1, b1, A, U, N);
        agg_kernel<64><<<(N * 64) / 256, 256, 0, stream>>>(A, U, knn8, h1, N);

        sqnorm_kernel<64><<<qBlocks, 256, 0, stream>>>(h1, sq, N);
        knn_partial_kernel<64><<<qBlocks * L1SEG, 256, 0, stream>>>(h1, sq, pd8, pidx8, N);
        knn_merge_kernel<<<qBlocks, 256, 0, stream>>>(pd8, pidx8, knn8, N, L1SEG);
        proj_kernel<64, 64><<<(N * 64) / 256, 256, 0, stream>>>(h1, W2, b2, A, U, N);
        agg_kernel<64><<<(N * 64) / 256, 256, 0, stream>>>(A, U, knn8, h2, N);

        sqnorm_kernel<64><<<qBlocks, 256, 0, stream>>>(h2, sq, N);
        knn_partial_kernel<64><<<qBlocks * L1SEG, 256, 0, stream>>>(h2, sq, pd8, pidx8, N);
        knn_merge_kernel<<<qBlocks, 256, 0, stream>>>(pd8, pidx8, knn8, N, L1SEG);
        proj_kernel<64, 128><<<(N * 128) / 256, 256, 0, stream>>>(h2, W3, b3, A, U, N);
        agg_kernel<128><<<(N * 128) / 256, 256, 0, stream>>>(A, U, knn8, out, N);
    }
}

// Round 5
// 3685.328 us; speedup vs baseline: 3.3250x; 3.3250x over previous
//
#include <hip/hip_runtime.h>
#include <math.h>

#define K_NN 20
#define NEG_SLOPE 0.2f

constexpr int NSEG = 8;   // segments per query; 8 sorted lists/query -> merge

// ---------------------------------------------------------------------------
__device__ __forceinline__ void insert_sorted(float (&dl)[K_NN], int (&il)[K_NN],
                                              float d, int idx) {
    if (d < dl[K_NN - 1]) {
        dl[K_NN - 1] = d; il[K_NN - 1] = idx;
#pragma unroll
        for (int p = K_NN - 1; p > 0; --p) {
            if (dl[p] < dl[p - 1]) {   // strict <: earlier (lower-index) ties stay first
                float td = dl[p]; dl[p] = dl[p - 1]; dl[p - 1] = td;
                int   ti = il[p]; il[p] = il[p - 1]; il[p - 1] = ti;
            }
        }
    }
}

// ---------------------------------------------------------------------------
// sq[i] = sum_c x[i][c]^2   (ascending-c FMA chain; must match dot order)
template<int C>
__global__ __launch_bounds__(256) void sqnorm_kernel(const float* __restrict__ x,
                                                     float* __restrict__ sq, int N) {
    int i = blockIdx.x * 256 + threadIdx.x;
    if (i < N) {
        float s = 0.f;
#pragma unroll
        for (int c = 0; c < C; ++c) { float v = x[i * C + c]; s += v * v; }
        sq[i] = s;
    }
}

// x4[i] = {x,y,z, sq}  (same fp chain as sqnorm<3>)
__global__ __launch_bounds__(256) void pack3_kernel(const float* __restrict__ x,
                                                    float4* __restrict__ x4, int N) {
    int i = blockIdx.x * 256 + threadIdx.x;
    if (i < N) {
        float a = x[i * 3], b = x[i * 3 + 1], c = x[i * 3 + 2];
        float s = a * a; s += b * b; s += c * c;
        x4[i] = make_float4(a, b, c, s);
    }
}

// ---------------------------------------------------------------------------
// Layer-1 kNN: round-1 structure (thread = query, 8 segments, LDS point tile)
// + buffered insert: candidates go to a per-thread LDS column (own bank),
// 20-deep bubble runs only on rare wave-wide drains.
__global__ __launch_bounds__(256) void knn3_kernel(const float4* __restrict__ x4,
                                                   float* __restrict__ pdist,
                                                   int* __restrict__ pidx, int N) {
    __shared__ float4 tile4[128];
    __shared__ float bufD[16 * 256];
    __shared__ int   bufI[16 * 256];
    const int tid = threadIdx.x;
    const int q   = blockIdx.x * 256 + tid;
    const int seg = blockIdx.y;
    const int segLen = N / NSEG;
    const int j0  = seg * segLen;

    const float4 qv = x4[q];

    float dl[K_NN]; int il[K_NN];
#pragma unroll
    for (int p = 0; p < K_NN; ++p) { dl[p] = __builtin_inff(); il[p] = 0; }
    int cnt = 0;

    for (int t0 = 0; t0 < segLen; t0 += 128) {
        __syncthreads();
        if (tid < 128) tile4[tid] = x4[j0 + t0 + tid];
        __syncthreads();
        for (int jj = 0; jj < 128; jj += 8) {
#pragma unroll
            for (int u = 0; u < 8; ++u) {
                float4 pv = tile4[jj + u];                     // b128 broadcast
                float dot = qv.x * pv.x; dot += qv.y * pv.y; dot += qv.z * pv.z;
                float d = (qv.w - 2.f * dot) + pv.w;
                if (d < dl[K_NN - 1]) {
                    bufD[tid + 256 * cnt] = d;
                    bufI[tid + 256 * cnt] = j0 + t0 + jj + u;
                    ++cnt;
                }
            }
            if (__any(cnt >= 8)) {                             // depth 16, +8/window
                for (int u2 = 0; u2 < cnt; ++u2)
                    insert_sorted(dl, il, bufD[tid + 256 * u2], bufI[tid + 256 * u2]);
                cnt = 0;
            }
        }
    }
    for (int u2 = 0; u2 < cnt; ++u2)
        insert_sorted(dl, il, bufD[tid + 256 * u2], bufI[tid + 256 * u2]);

    const size_t base = ((size_t)q * NSEG + seg) * K_NN;
#pragma unroll
    for (int p = 0; p < K_NN; ++p) { pdist[base + p] = dl[p]; pidx[base + p] = il[p]; }
}

// ---------------------------------------------------------------------------
// xT[c][i] = x[i][c]  (C = 64)
__global__ __launch_bounds__(256) void transpose64_kernel(const float* __restrict__ xin,
                                                          float* __restrict__ xT, int N) {
    int i = blockIdx.x * 256 + threadIdx.x;
    int c = blockIdx.y;
    xT[(size_t)c * N + i] = xin[(size_t)i * 64 + c];
}

// ---------------------------------------------------------------------------
// Fused distance-GEMM + top-20 selection, C = 64.
// Block: 128 queries x 2048-point segment, 16 tiles of 128 points.
// GEMM: 8x8/thread register tile (VALU-bound, exact round-3 arithmetic).
// Transpose: acc -> Dth[128q][64p] per point-half through LDS.
// Select: thread s < 128 owns query q0+s, ONE register top-20 per block,
// buffered-insert drains. 1 block/CU (108 KB LDS) is fine: FMA saturates
// at 1 wave/SIMD; pT staging latency hidden by reg double-buffer.
__global__ __launch_bounds__(256, 1) void knn_fused64_kernel(const float* __restrict__ xT,
                                                             const float* __restrict__ sq,
                                                             float* __restrict__ pdist,
                                                             int* __restrict__ pidx, int N) {
    __shared__ float qT[64][132];
    __shared__ float pT[64][132];
    __shared__ float Dth[128][68];
    __shared__ float bufD[8 * 128];
    __shared__ int   bufI[8 * 128];

    const int tid = threadIdx.x;
    const int q0  = blockIdx.x * 128;
    const int seg = blockIdx.y;
    const int segLen = N / NSEG;          // 2048
    const int j0  = seg * segLen;
    const int nT  = segLen / 128;         // 16

    const int qg = tid >> 4, pg = tid & 15;
    const int qcol = qg * 8, pcol = pg * 8;

    // stage qT once: 2048 float4, 8 per thread; v -> row c=v>>5, col (v&31)*4
#pragma unroll
    for (int k = 0; k < 8; ++k) {
        int v = tid + 256 * k; int c = v >> 5; int dd = (v & 31) * 4;
        *(float4*)&qT[c][dd] = *(const float4*)&xT[(size_t)c * N + q0 + dd];
    }
    float qsv[8];
    *(float4*)&qsv[0] = *(const float4*)&sq[q0 + qcol];
    *(float4*)&qsv[4] = *(const float4*)&sq[q0 + qcol + 4];

    float dl[K_NN]; int il[K_NN];
#pragma unroll
    for (int p = 0; p < K_NN; ++p) { dl[p] = __builtin_inff(); il[p] = 0; }
    int cnt = 0;

    // prologue: stage pT tile 0
#pragma unroll
    for (int k = 0; k < 8; ++k) {
        int v = tid + 256 * k; int c = v >> 5; int dd = (v & 31) * 4;
        *(float4*)&pT[c][dd] = *(const float4*)&xT[(size_t)c * N + j0 + dd];
    }
    __syncthreads();

    for (int t = 0; t < nT; ++t) {
        const int jb = j0 + t * 128;
        const bool more = (t + 1 < nT);

        float4 pld[8];
        if (more) {
#pragma unroll
            for (int k = 0; k < 8; ++k) {
                int v = tid + 256 * k; int c = v >> 5; int dd = (v & 31) * 4;
                pld[k] = *(const float4*)&xT[(size_t)c * N + jb + 128 + dd];
            }
        }
        float psv[8];
        *(float4*)&psv[0] = *(const float4*)&sq[jb + pcol];
        *(float4*)&psv[4] = *(const float4*)&sq[jb + pcol + 4];

        // ---- GEMM: ascending-c fmac chains (bit-identical to rounds 1-3) ----
        float acc[8][8];
#pragma unroll
        for (int i = 0; i < 8; ++i)
#pragma unroll
            for (int j = 0; j < 8; ++j) acc[i][j] = 0.f;

#pragma unroll 4
        for (int c = 0; c < 64; ++c) {
            float4 qa  = *(const float4*)&qT[c][qcol];
            float4 qb4 = *(const float4*)&qT[c][qcol + 4];
            float4 pa  = *(const float4*)&pT[c][pcol];
            float4 pb4 = *(const float4*)&pT[c][pcol + 4];
            float qf[8] = {qa.x, qa.y, qa.z, qa.w, qb4.x, qb4.y, qb4.z, qb4.w};
            float pf[8] = {pa.x, pa.y, pa.z, pa.w, pb4.x, pb4.y, pb4.z, pb4.w};
#pragma unroll
            for (int i = 0; i < 8; ++i)
#pragma unroll
                for (int j = 0; j < 8; ++j) acc[i][j] += qf[i] * pf[j];
        }

        // ---- two point-half phases: transpose + select ----
#pragma unroll
        for (int h = 0; h < 2; ++h) {
            if ((pg >> 3) == h) {                   // writers: points 64h..64h+63
                const int colb = (pg & 7) * 8;
#pragma unroll
                for (int i = 0; i < 8; ++i) {
                    float4 w0, w1;
                    w0.x = (qsv[i] - 2.f * acc[i][0]) + psv[0];
                    w0.y = (qsv[i] - 2.f * acc[i][1]) + psv[1];
                    w0.z = (qsv[i] - 2.f * acc[i][2]) + psv[2];
                    w0.w = (qsv[i] - 2.f * acc[i][3]) + psv[3];
                    w1.x = (qsv[i] - 2.f * acc[i][4]) + psv[4];
                    w1.y = (qsv[i] - 2.f * acc[i][5]) + psv[5];
                    w1.z = (qsv[i] - 2.f * acc[i][6]) + psv[6];
                    w1.w = (qsv[i] - 2.f * acc[i][7]) + psv[7];
                    *(float4*)&Dth[qcol + i][colb]     = w0;
                    *(float4*)&Dth[qcol + i][colb + 4] = w1;
                }
            }
            __syncthreads();
            if (tid < 128) {                        // select: query q0+tid
                const int jbase0 = jb + 64 * h;
                for (int m = 0; m < 16; ++m) {
                    float4 v = *(const float4*)&Dth[tid][m * 4];
                    int jb4 = jbase0 + m * 4;
                    float thr = dl[K_NN - 1];
                    if (v.x < thr) { bufD[tid + 128 * cnt] = v.x; bufI[tid + 128 * cnt] = jb4;     ++cnt; }
                    if (v.y < thr) { bufD[tid + 128 * cnt] = v.y; bufI[tid + 128 * cnt] = jb4 + 1; ++cnt; }
                    if (v.z < thr) { bufD[tid + 128 * cnt] = v.z; bufI[tid + 128 * cnt] = jb4 + 2; ++cnt; }
                    if (v.w < thr) { bufD[tid + 128 * cnt] = v.w; bufI[tid + 128 * cnt] = jb4 + 3; ++cnt; }
                    if (__any(cnt >= 5)) {          // depth 8, +4/window
                        for (int u2 = 0; u2 < cnt; ++u2)
                            insert_sorted(dl, il, bufD[tid + 128 * u2], bufI[tid + 128 * u2]);
                        cnt = 0;
                    }
                }
            }
            __syncthreads();
        }

        if (more) {
#pragma unroll
            for (int k = 0; k < 8; ++k) {
                int v = tid + 256 * k; int c = v >> 5; int dd = (v & 31) * 4;
                *(float4*)&pT[c][dd] = pld[k];
            }
            __syncthreads();
        }
    }

    if (tid < 128) {
        for (int u2 = 0; u2 < cnt; ++u2)
            insert_sorted(dl, il, bufD[tid + 128 * u2], bufI[tid + 128 * u2]);
        const size_t base = ((size_t)(q0 + tid) * NSEG + seg) * K_NN;
#pragma unroll
        for (int p = 0; p < K_NN; ++p) { pdist[base + p] = dl[p]; pidx[base + p] = il[p]; }
    }
}

// ---------------------------------------------------------------------------
// Merge NSEG sorted partial lists -> final top-20 per query.
__global__ __launch_bounds__(256) void knn_merge_kernel(const float* __restrict__ pdist,
                                                        const int* __restrict__ pidx,
                                                        int* __restrict__ knn, int N) {
    int q = blockIdx.x * 256 + threadIdx.x;
    if (q >= N) return;
    float dl[K_NN]; int il[K_NN];
#pragma unroll
    for (int p = 0; p < K_NN; ++p) { dl[p] = __builtin_inff(); il[p] = 0; }

    for (int s = 0; s < NSEG; ++s) {
        const long base = ((long)q * NSEG + s) * K_NN;
        for (int p = 0; p < K_NN; ++p) {
            float d = pdist[base + p];
            if (!(d < dl[K_NN - 1])) break;   // list sorted ascending
            insert_sorted(dl, il, d, pidx[base + p]);
        }
    }
#pragma unroll
    for (int p = 0; p < K_NN; ++p) knn[(long)q * K_NN + p] = il[p];
}

// ---------------------------------------------------------------------------
template<int C, int F>
__global__ __launch_bounds__(256) void proj_kernel(const float* __restrict__ x,
                                                   const float* __restrict__ W,
                                                   const float* __restrict__ b,
                                                   float* __restrict__ A,
                                                   float* __restrict__ U, int N) {
    int gid = blockIdx.x * 256 + threadIdx.x;
    int i = gid / F, f = gid % F;
    if (i >= N) return;
    float a = b[f], u = 0.f;
#pragma unroll
    for (int c = 0; c < C; ++c) {
        float xv = x[i * C + c];
        a += xv * W[c * F + f];
        u += xv * W[(C + c) * F + f];
    }
    A[(long)i * F + f] = a;
    U[(long)i * F + f] = u;
}

template<int F>
__global__ __launch_bounds__(256) void agg_kernel(const float* __restrict__ A,
                                                  const float* __restrict__ U,
                                                  const int* __restrict__ knn,
                                                  float* __restrict__ out, int N) {
    int gid = blockIdx.x * 256 + threadIdx.x;
    int i = gid / F, f = gid % F;
    if (i >= N) return;
    float a = A[(long)i * F + f] - U[(long)i * F + f];
    float m = -__builtin_inff();
#pragma unroll
    for (int k = 0; k < K_NN; ++k) {
        int j = knn[(long)i * K_NN + k];
        float v = a + U[(long)j * F + f];
        v = fmaxf(v, v * NEG_SLOPE);
        m = fmaxf(m, v);
    }
    out[(long)i * F + f] = m;
}

// ---------------------------------------------------------------------------
extern "C" void kernel_launch(void* const* d_in, const int* in_sizes, int n_in,
                              void* d_out, int out_size, void* d_ws, size_t ws_size,
                              hipStream_t stream) {
    const float* x  = (const float*)d_in[0];
    const float* W1 = (const float*)d_in[1];
    const float* b1 = (const float*)d_in[2];
    const float* W2 = (const float*)d_in[3];
    const float* b2 = (const float*)d_in[4];
    const float* W3 = (const float*)d_in[5];
    const float* b3 = (const float*)d_in[6];
    const int N = in_sizes[0] / 3;  // 16384

    // workspace (~52 MB of floats; ws proven >= 182 MB in round 4)
    float* ws  = (float*)d_ws;
    float* sq  = ws;                                   // N
    float* A   = sq + N;                               // 128N
    float* U   = A + (size_t)N * 128;                  // 128N
    float* h1  = U + (size_t)N * 128;                  // 64N
    float* h2  = h1 + (size_t)N * 64;                  // 64N
    float4* x4 = (float4*)(h2 + (size_t)N * 64);       // 4N
    float* xT  = (float*)(x4 + N);                     // 64N
    float* pd  = xT + (size_t)N * 64;                  // 160N
    int* pidx  = (int*)(pd + (size_t)N * NSEG * K_NN); // 160N
    int* knn   = pidx + (size_t)N * NSEG * K_NN;       // 20N
    float* out = (float*)d_out;

    const int qBlocks = N / 256;

    // ---- Layer 1 (C=3 -> F=64) ----
    pack3_kernel<<<qBlocks, 256, 0, stream>>>(x, x4, N);
    knn3_kernel<<<dim3(qBlocks, NSEG), 256, 0, stream>>>(x4, pd, pidx, N);
    knn_merge_kernel<<<qBlocks, 256, 0, stream>>>(pd, pidx, knn, N);
    proj_kernel<3, 64><<<(N * 64) / 256, 256, 0, stream>>>(x, W1, b1, A, U, N);
    agg_kernel<64><<<(N * 64) / 256, 256, 0, stream>>>(A, U, knn, h1, N);

    // ---- Layer 2 (C=64 -> F=64) ----
    sqnorm_kernel<64><<<qBlocks, 256, 0, stream>>>(h1, sq, N);
    transpose64_kernel<<<dim3(qBlocks, 64), 256, 0, stream>>>(h1, xT, N);
    knn_fused64_kernel<<<dim3(N / 128, NSEG), 256, 0, stream>>>(xT, sq, pd, pidx, N);
    knn_merge_kernel<<<qBlocks, 256, 0, stream>>>(pd, pidx, knn, N);
    proj_kernel<64, 64><<<(N * 64) / 256, 256, 0, stream>>>(h1, W2, b2, A, U, N);
    agg_kernel<64><<<(N * 64) / 256, 256, 0, stream>>>(A, U, knn, h2, N);

    // ---- Layer 3 (C=64 -> F=128) ----
    sqnorm_kernel<64><<<qBlocks, 256, 0, stream>>>(h2, sq, N);
    transpose64_kernel<<<dim3(qBlocks, 64), 256, 0, stream>>>(h2, xT, N);
    knn_fused64_kernel<<<dim3(N / 128, NSEG), 256, 0, stream>>>(xT, sq, pd, pidx, N);
    knn_merge_kernel<<<qBlocks, 256, 0, stream>>>(pd, pidx, knn, N);
    proj_kernel<64, 128><<<(N * 128) / 256, 256, 0, stream>>>(h2, W3, b3, A, U, N);
    agg_kernel<128><<<(N * 128) / 256, 256, 0, stream>>>(A, U, knn, out, N);
}

// Round 6
// 2178.495 us; speedup vs baseline: 5.6248x; 1.6917x over previous
//
#include <hip/hip_runtime.h>
#include <math.h>

#define K_NN 20
#define NEG_SLOPE 0.2f

constexpr int NSEG = 8;   // segments per query -> 8 sorted partial lists -> merge

// ---------------------------------------------------------------------------
__device__ __forceinline__ void insert_sorted(float (&dl)[K_NN], int (&il)[K_NN],
                                              float d, int idx) {
    if (d < dl[K_NN - 1]) {
        dl[K_NN - 1] = d; il[K_NN - 1] = idx;
#pragma unroll
        for (int p = K_NN - 1; p > 0; --p) {
            if (dl[p] < dl[p - 1]) {   // strict <: earlier (lower-index) ties stay first
                float td = dl[p]; dl[p] = dl[p - 1]; dl[p - 1] = td;
                int   ti = il[p]; il[p] = il[p - 1]; il[p - 1] = ti;
            }
        }
    }
}

// ---------------------------------------------------------------------------
// sq[i] = sum_c x[i][c]^2   (ascending-c FMA chain; must match dot order)
template<int C>
__global__ __launch_bounds__(256) void sqnorm_kernel(const float* __restrict__ x,
                                                     float* __restrict__ sq, int N) {
    int i = blockIdx.x * 256 + threadIdx.x;
    if (i < N) {
        float s = 0.f;
#pragma unroll
        for (int c = 0; c < C; ++c) { float v = x[i * C + c]; s += v * v; }
        sq[i] = s;
    }
}

// x4[i] = {x,y,z, sq}  (same fp chain as sqnorm<3>)
__global__ __launch_bounds__(256) void pack3_kernel(const float* __restrict__ x,
                                                    float4* __restrict__ x4, int N) {
    int i = blockIdx.x * 256 + threadIdx.x;
    if (i < N) {
        float a = x[i * 3], b = x[i * 3 + 1], c = x[i * 3 + 2];
        float s = a * a; s += b * b; s += c * c;
        x4[i] = make_float4(a, b, c, s);
    }
}

// ---------------------------------------------------------------------------
// Layer-1 tau: exact top-20 over points [0,2048); tau = guarded 20th distance.
__global__ __launch_bounds__(128) void tau3_kernel(const float4* __restrict__ x4,
                                                   float* __restrict__ tau, int N) {
    __shared__ float bufD[16 * 128];
    __shared__ int   bufI[16 * 128];
    const int tid = threadIdx.x;
    const int q   = blockIdx.x * 128 + tid;
    const float4 qv = x4[q];

    float dl[K_NN]; int il[K_NN];
#pragma unroll
    for (int p = 0; p < K_NN; ++p) { dl[p] = __builtin_inff(); il[p] = 0; }
    int cnt = 0;

    for (int j0 = 0; j0 < 2048; j0 += 8) {
#pragma unroll
        for (int u = 0; u < 8; ++u) {
            float4 pv = x4[j0 + u];
            float dot = qv.x * pv.x; dot += qv.y * pv.y; dot += qv.z * pv.z;
            float d = (qv.w - 2.f * dot) + pv.w;
            if (d < dl[K_NN - 1]) { bufD[tid + 128 * cnt] = d; bufI[tid + 128 * cnt] = j0 + u; ++cnt; }
        }
        if (__any(cnt >= 8)) {
            for (int u2 = 0; u2 < cnt; ++u2)
                insert_sorted(dl, il, bufD[tid + 128 * u2], bufI[tid + 128 * u2]);
            cnt = 0;
        }
    }
    for (int u2 = 0; u2 < cnt; ++u2)
        insert_sorted(dl, il, bufD[tid + 128 * u2], bufI[tid + 128 * u2]);

    tau[q] = dl[K_NN - 1] * 1.000002f + 2e-6f * qv.w;
}

// ---------------------------------------------------------------------------
// Layer-1 main kNN: thread = query, 8 segments, warm tau gate (d <= tau).
__global__ __launch_bounds__(256) void knn3w_kernel(const float4* __restrict__ x4,
                                                    const float* __restrict__ tau,
                                                    float* __restrict__ pdist,
                                                    int* __restrict__ pidx, int N) {
    __shared__ float4 tile4[128];
    __shared__ float bufD[16 * 256];
    __shared__ int   bufI[16 * 256];
    const int tid = threadIdx.x;
    const int q   = blockIdx.x * 256 + tid;
    const int seg = blockIdx.y;
    const int segLen = N / NSEG;
    const int j0  = seg * segLen;

    const float4 qv = x4[q];
    const float  tq = tau[q];

    float dl[K_NN]; int il[K_NN];
#pragma unroll
    for (int p = 0; p < K_NN; ++p) { dl[p] = __builtin_inff(); il[p] = 0; }
    int cnt = 0;

    for (int t0 = 0; t0 < segLen; t0 += 128) {
        __syncthreads();
        if (tid < 128) tile4[tid] = x4[j0 + t0 + tid];
        __syncthreads();
        for (int jj = 0; jj < 128; jj += 8) {
#pragma unroll
            for (int u = 0; u < 8; ++u) {
                float4 pv = tile4[jj + u];
                float dot = qv.x * pv.x; dot += qv.y * pv.y; dot += qv.z * pv.z;
                float d = (qv.w - 2.f * dot) + pv.w;
                if (d <= tq && d < dl[K_NN - 1]) {
                    bufD[tid + 256 * cnt] = d;
                    bufI[tid + 256 * cnt] = j0 + t0 + jj + u;
                    ++cnt;
                }
            }
            if (__any(cnt >= 8)) {
                for (int u2 = 0; u2 < cnt; ++u2)
                    insert_sorted(dl, il, bufD[tid + 256 * u2], bufI[tid + 256 * u2]);
                cnt = 0;
            }
        }
    }
    for (int u2 = 0; u2 < cnt; ++u2)
        insert_sorted(dl, il, bufD[tid + 256 * u2], bufI[tid + 256 * u2]);

    const size_t base = ((size_t)q * NSEG + seg) * K_NN;
#pragma unroll
    for (int p = 0; p < K_NN; ++p) { pdist[base + p] = dl[p]; pidx[base + p] = il[p]; }
}

// ---------------------------------------------------------------------------
// C=64 tau from previous layer's neighbor graph: tau_q = max d_new(q, prev_nbr).
// Bit-identical fp chain to the fused kernel (ascending-c fmac, (qs-2dot)+ps).
__global__ __launch_bounds__(256) void tau64_kernel(const float* __restrict__ feat,
                                                    const float* __restrict__ sq,
                                                    const int* __restrict__ knn,
                                                    float* __restrict__ tau, int N) {
    int q = blockIdx.x * 256 + threadIdx.x;
    if (q >= N) return;
    const float4* qrow = (const float4*)&feat[(size_t)q * 64];
    float4 qf[16];
#pragma unroll
    for (int m = 0; m < 16; ++m) qf[m] = qrow[m];
    const float qsq = sq[q];
    float t = 0.f;
    for (int k = 0; k < K_NN; ++k) {
        int j = knn[(size_t)q * K_NN + k];
        const float4* prow = (const float4*)&feat[(size_t)j * 64];
        float dot = 0.f;
#pragma unroll
        for (int m = 0; m < 16; ++m) {
            float4 pv = prow[m];
            dot += qf[m].x * pv.x; dot += qf[m].y * pv.y;
            dot += qf[m].z * pv.z; dot += qf[m].w * pv.w;
        }
        float d = (qsq - 2.f * dot) + sq[j];
        t = fmaxf(t, d);
    }
    tau[q] = t * 1.000002f + 2e-6f * qsq;
}

// ---------------------------------------------------------------------------
// xT[c][i] = x[i][c]  (C = 64)
__global__ __launch_bounds__(256) void transpose64_kernel(const float* __restrict__ xin,
                                                          float* __restrict__ xT, int N) {
    int i = blockIdx.x * 256 + threadIdx.x;
    int c = blockIdx.y;
    xT[(size_t)c * N + i] = xin[(size_t)i * 64 + c];
}

// ---------------------------------------------------------------------------
// Fused distance-GEMM + warm top-20 selection, C = 64. 76 KB LDS -> 2 blocks/CU.
// 128q x 2048p segment, 16 tiles of 128p; 8x8 register tile; pT c-chunked
// (8 rows) with the round-3-verified swizzle s(col)=col+4*(col>>5) (0 bank
// conflicts) + register prefetch; Dth[128][64] XOR-swizzled transpose buffer;
// selection by 128 threads with LDS candidate buffer + rare wave drains.
__global__ __launch_bounds__(256, 2) void fused64w_kernel(const float* __restrict__ xT,
                                                          const float* __restrict__ sq,
                                                          const float* __restrict__ tau,
                                                          float* __restrict__ pdist,
                                                          int* __restrict__ pidx, int N) {
    __shared__ float qT[64][132];
    __shared__ float pTc[8][140];
    __shared__ float Dth[128][64];
    __shared__ float psq_s[140];
    __shared__ float bufD[8 * 128];
    __shared__ unsigned short bufS[8 * 128];

    const int tid = threadIdx.x;
    const int q0  = blockIdx.x * 128;
    const int seg = blockIdx.y;
    const int segLen = N / NSEG;          // 2048
    const int j0  = seg * segLen;

    const int qg = tid >> 4, pg = tid & 15;
    const int qcol = qg * 8;
    const int pcol = pg * 8 + 4 * (pg >> 2);   // s(pg*8)

    // ---- stage qT once (broadcast reads later -> no swizzle needed) ----
#pragma unroll
    for (int k = 0; k < 8; ++k) {
        int v = tid + 256 * k; int c = v >> 5; int dd = (v & 31) * 4;
        *(float4*)&qT[c][dd] = *(const float4*)&xT[(size_t)c * N + q0 + dd];
    }
    float qsv[8];
    *(float4*)&qsv[0] = *(const float4*)&sq[q0 + qcol];
    *(float4*)&qsv[4] = *(const float4*)&sq[q0 + qcol + 4];
    const float tq = (tid < 128) ? tau[q0 + tid] : 0.f;

    float dl[K_NN]; int il[K_NN];
#pragma unroll
    for (int p = 0; p < K_NN; ++p) { dl[p] = __builtin_inff(); il[p] = 0; }
    int cnt = 0;

    const int stc = tid >> 5;             // pTc stage row 0..7
    const int std_ = (tid & 31) * 4;      // pTc stage col
    const int sts = std_ + 4 * (std_ >> 5);

    for (int t = 0; t < 16; ++t) {
        const int jb = j0 + t * 128;

        float4 pnext = *(const float4*)&xT[(size_t)stc * N + jb + std_];
        float acc[8][8];
#pragma unroll
        for (int i = 0; i < 8; ++i)
#pragma unroll
            for (int j = 0; j < 8; ++j) acc[i][j] = 0.f;

        for (int cc = 0; cc < 8; ++cc) {
            __syncthreads();              // pTc consumers of prev chunk done
            *(float4*)&pTc[stc][sts] = pnext;
            if (cc == 0 && tid < 128) psq_s[tid + 4 * (tid >> 5)] = sq[jb + tid];
            __syncthreads();
            if (cc < 7)
                pnext = *(const float4*)&xT[(size_t)(cc * 8 + 8 + stc) * N + jb + std_];

#pragma unroll
            for (int c8 = 0; c8 < 8; ++c8) {
                const int c = cc * 8 + c8;
                float4 qa  = *(const float4*)&qT[c][qcol];
                float4 qb4 = *(const float4*)&qT[c][qcol + 4];
                float4 pa  = *(const float4*)&pTc[c8][pcol];
                float4 pb4 = *(const float4*)&pTc[c8][pcol + 4];
                float qf[8] = {qa.x, qa.y, qa.z, qa.w, qb4.x, qb4.y, qb4.z, qb4.w};
                float pf[8] = {pa.x, pa.y, pa.z, pa.w, pb4.x, pb4.y, pb4.z, pb4.w};
#pragma unroll
                for (int i = 0; i < 8; ++i)
#pragma unroll
                    for (int j = 0; j < 8; ++j) acc[i][j] += qf[i] * pf[j];
            }
        }

        float psv[8];
        *(float4*)&psv[0] = *(const float4*)&psq_s[pcol];
        *(float4*)&psv[4] = *(const float4*)&psq_s[pcol + 4];

#pragma unroll
        for (int h = 0; h < 2; ++h) {
            __syncthreads();              // previous half's readers done
            if ((pg >> 3) == h) {         // writers: points 64h .. 64h+63
                const int colb = (pg & 7) * 8;
#pragma unroll
                for (int i = 0; i < 8; ++i) {
                    float4 w0, w1;
                    w0.x = (qsv[i] - 2.f * acc[i][0]) + psv[0];
                    w0.y = (qsv[i] - 2.f * acc[i][1]) + psv[1];
                    w0.z = (qsv[i] - 2.f * acc[i][2]) + psv[2];
                    w0.w = (qsv[i] - 2.f * acc[i][3]) + psv[3];
                    w1.x = (qsv[i] - 2.f * acc[i][4]) + psv[4];
                    w1.y = (qsv[i] - 2.f * acc[i][5]) + psv[5];
                    w1.z = (qsv[i] - 2.f * acc[i][6]) + psv[6];
                    w1.w = (qsv[i] - 2.f * acc[i][7]) + psv[7];
                    int cb = colb ^ (i << 3);          // XOR row-swizzle
                    *(float4*)&Dth[qcol + i][cb]     = w0;
                    *(float4*)&Dth[qcol + i][cb + 4] = w1;
                }
            }
            __syncthreads();
            if (tid < 128) {              // select: query q0+tid over 64 points
                const int lbase = t * 128 + 64 * h;
                for (int m = 0; m < 16; ++m) {
                    float4 v = *(const float4*)&Dth[tid][(m * 4) ^ ((tid & 7) << 3)];
                    int lj = lbase + m * 4;
                    float thr = dl[K_NN - 1];
                    if (v.x <= tq && v.x < thr) { bufD[tid + 128 * cnt] = v.x; bufS[tid + 128 * cnt] = (unsigned short)(lj);     ++cnt; }
                    if (v.y <= tq && v.y < thr) { bufD[tid + 128 * cnt] = v.y; bufS[tid + 128 * cnt] = (unsigned short)(lj + 1); ++cnt; }
                    if (v.z <= tq && v.z < thr) { bufD[tid + 128 * cnt] = v.z; bufS[tid + 128 * cnt] = (unsigned short)(lj + 2); ++cnt; }
                    if (v.w <= tq && v.w < thr) { bufD[tid + 128 * cnt] = v.w; bufS[tid + 128 * cnt] = (unsigned short)(lj + 3); ++cnt; }
                    if (__any(cnt >= 5)) {
                        for (int u2 = 0; u2 < cnt; ++u2)
                            insert_sorted(dl, il, bufD[tid + 128 * u2], j0 + (int)bufS[tid + 128 * u2]);
                        cnt = 0;
                    }
                }
            }
        }
    }

    if (tid < 128) {
        for (int u2 = 0; u2 < cnt; ++u2)
            insert_sorted(dl, il, bufD[tid + 128 * u2], j0 + (int)bufS[tid + 128 * u2]);
        const size_t base = ((size_t)(q0 + tid) * NSEG + seg) * K_NN;
#pragma unroll
        for (int p = 0; p < K_NN; ++p) { pdist[base + p] = dl[p]; pidx[base + p] = il[p]; }
    }
}

// ---------------------------------------------------------------------------
// Merge NSEG sorted partial lists -> final top-20 per query.
__global__ __launch_bounds__(256) void knn_merge_kernel(const float* __restrict__ pdist,
                                                        const int* __restrict__ pidx,
                                                        int* __restrict__ knn, int N) {
    int q = blockIdx.x * 256 + threadIdx.x;
    if (q >= N) return;
    float dl[K_NN]; int il[K_NN];
#pragma unroll
    for (int p = 0; p < K_NN; ++p) { dl[p] = __builtin_inff(); il[p] = 0; }

    for (int s = 0; s < NSEG; ++s) {
        const long base = ((long)q * NSEG + s) * K_NN;
        for (int p = 0; p < K_NN; ++p) {
            float d = pdist[base + p];
            if (!(d < dl[K_NN - 1])) break;   // list sorted ascending; inf tail exits
            insert_sorted(dl, il, d, pidx[base + p]);
        }
    }
#pragma unroll
    for (int p = 0; p < K_NN; ++p) knn[(long)q * K_NN + p] = il[p];
}

// ---------------------------------------------------------------------------
template<int C, int F>
__global__ __launch_bounds__(256) void proj_kernel(const float* __restrict__ x,
                                                   const float* __restrict__ W,
                                                   const float* __restrict__ b,
                                                   float* __restrict__ A,
                                                   float* __restrict__ U, int N) {
    int gid = blockIdx.x * 256 + threadIdx.x;
    int i = gid / F, f = gid % F;
    if (i >= N) return;
    float a = b[f], u = 0.f;
#pragma unroll
    for (int c = 0; c < C; ++c) {
        float xv = x[i * C + c];
        a += xv * W[c * F + f];
        u += xv * W[(C + c) * F + f];
    }
    A[(long)i * F + f] = a;
    U[(long)i * F + f] = u;
}

template<int F>
__global__ __launch_bounds__(256) void agg_kernel(const float* __restrict__ A,
                                                  const float* __restrict__ U,
                                                  const int* __restrict__ knn,
                                                  float* __restrict__ out, int N) {
    int gid = blockIdx.x * 256 + threadIdx.x;
    int i = gid / F, f = gid % F;
    if (i >= N) return;
    float a = A[(long)i * F + f] - U[(long)i * F + f];
    float m = -__builtin_inff();
#pragma unroll
    for (int k = 0; k < K_NN; ++k) {
        int j = knn[(long)i * K_NN + k];
        float v = a + U[(long)j * F + f];
        v = fmaxf(v, v * NEG_SLOPE);
        m = fmaxf(m, v);
    }
    out[(long)i * F + f] = m;
}

// ---------------------------------------------------------------------------
extern "C" void kernel_launch(void* const* d_in, const int* in_sizes, int n_in,
                              void* d_out, int out_size, void* d_ws, size_t ws_size,
                              hipStream_t stream) {
    const float* x  = (const float*)d_in[0];
    const float* W1 = (const float*)d_in[1];
    const float* b1 = (const float*)d_in[2];
    const float* W2 = (const float*)d_in[3];
    const float* b2 = (const float*)d_in[4];
    const float* W3 = (const float*)d_in[5];
    const float* b3 = (const float*)d_in[6];
    const int N = in_sizes[0] / 3;  // 16384

    // workspace (~52 MB; proven >= 182 MB available in round 4)
    float* ws  = (float*)d_ws;
    float* sq  = ws;                                   // N
    float* A   = sq + N;                               // 128N
    float* U   = A + (size_t)N * 128;                  // 128N
    float* h1  = U + (size_t)N * 128;                  // 64N
    float* h2  = h1 + (size_t)N * 64;                  // 64N
    float4* x4 = (float4*)(h2 + (size_t)N * 64);       // 4N
    float* xT  = (float*)(x4 + N);                     // 64N
    float* tau = xT + (size_t)N * 64;                  // N
    float* pd  = tau + N;                              // 160N
    int* pidx  = (int*)(pd + (size_t)N * NSEG * K_NN); // 160N
    int* knn   = pidx + (size_t)N * NSEG * K_NN;       // 20N
    float* out = (float*)d_out;

    const int qBlocks = N / 256;

    // ---- Layer 1 (C=3 -> F=64) ----
    pack3_kernel<<<qBlocks, 256, 0, stream>>>(x, x4, N);
    tau3_kernel<<<N / 128, 128, 0, stream>>>(x4, tau, N);
    knn3w_kernel<<<dim3(qBlocks, NSEG), 256, 0, stream>>>(x4, tau, pd, pidx, N);
    knn_merge_kernel<<<qBlocks, 256, 0, stream>>>(pd, pidx, knn, N);
    proj_kernel<3, 64><<<(N * 64) / 256, 256, 0, stream>>>(x, W1, b1, A, U, N);
    agg_kernel<64><<<(N * 64) / 256, 256, 0, stream>>>(A, U, knn, h1, N);

    // ---- Layer 2 (C=64 -> F=64) ----
    sqnorm_kernel<64><<<qBlocks, 256, 0, stream>>>(h1, sq, N);
    transpose64_kernel<<<dim3(qBlocks, 64), 256, 0, stream>>>(h1, xT, N);
    tau64_kernel<<<qBlocks, 256, 0, stream>>>(h1, sq, knn, tau, N);   // uses L1 graph
    fused64w_kernel<<<dim3(N / 128, NSEG), 256, 0, stream>>>(xT, sq, tau, pd, pidx, N);
    knn_merge_kernel<<<qBlocks, 256, 0, stream>>>(pd, pidx, knn, N);
    proj_kernel<64, 64><<<(N * 64) / 256, 256, 0, stream>>>(h1, W2, b2, A, U, N);
    agg_kernel<64><<<(N * 64) / 256, 256, 0, stream>>>(A, U, knn, h2, N);

    // ---- Layer 3 (C=64 -> F=128) ----
    sqnorm_kernel<64><<<qBlocks, 256, 0, stream>>>(h2, sq, N);
    transpose64_kernel<<<dim3(qBlocks, 64), 256, 0, stream>>>(h2, xT, N);
    tau64_kernel<<<qBlocks, 256, 0, stream>>>(h2, sq, knn, tau, N);   // uses L2 graph
    fused64w_kernel<<<dim3(N / 128, NSEG), 256, 0, stream>>>(xT, sq, tau, pd, pidx, N);
    knn_merge_kernel<<<qBlocks, 256, 0, stream>>>(pd, pidx, knn, N);
    proj_kernel<64, 128><<<(N * 128) / 256, 256, 0, stream>>>(h2, W3, b3, A, U, N);
    agg_kernel<128><<<(N * 128) / 256, 256, 0, stream>>>(A, U, knn, out, N);
}